// Round 1
// baseline (1311.473 us; speedup 1.0000x reference)
//
#include <hip/hip_runtime.h>

// SimpleCRA: B=16 L=4096 D=512, codebook 2048x512, WORD_LEN=2.
// Outputs (concat f32): indices[32768], embeddings[32768*512], loss[1].
//
// Strategy:
//  - stats kernel: cb_sq[k] and S[k] = ||cb[k]@W^T + b - cb[k]||^2  (1 GFLOP)
//  - main kernel: fused mean-pool + f32 distance GEMM (68.7 GFLOP, VALU-bound)
//    with per-row running argmin, then gather embeddings + loss from S[idx].
//  - f32 vector math mandatory: bf16 MFMA error (~4e-3 rel) would flip argmins.

#define D_DIM    512
#define K_CODES  2048
#define N_ROWS   32768          // B * L / WORD_LEN
#define BM       128
#define BN       128
#define BK       32
#define LDT      132            // padded LDS row stride (floats): breaks 8-way write conflicts
#define N_TILES  (K_CODES / BN) // 16
#define D_CHUNKS (D_DIM / BK)   // 16

// ---------------------------------------------------------------------------
// Kernel 1: codebook stats. 256 blocks x 256 threads, 8 codes per block.
// cb_sq[k] = sum_d cb[k,d]^2
// S[k]     = sum_e (dot(cb[k,:], W[e,:]) + pb[e] - cb[k,e])^2
// Also zeroes the loss accumulator (d_out is poisoned 0xAA before every launch).
// ---------------------------------------------------------------------------
__global__ __launch_bounds__(256, 1)
void cra_stats_kernel(const float* __restrict__ cb,
                      const float* __restrict__ W,
                      const float* __restrict__ pb,
                      float* __restrict__ cb_sq,
                      float* __restrict__ Sk,
                      float* __restrict__ loss_out)
{
    __shared__ float cbs[8 * D_DIM];   // 16 KB: 8 codebook rows
    __shared__ float red[256];
    const int tid = threadIdx.x;
    const int c0  = blockIdx.x * 8;

    if (blockIdx.x == 0 && tid == 0) loss_out[0] = 0.0f;

    // stage 8 contiguous codebook rows, coalesced float4
    {
        const float4* src = (const float4*)(cb + (size_t)c0 * D_DIM);
        float4* dst = (float4*)cbs;
        #pragma unroll
        for (int k = 0; k < 4; ++k) dst[tid + k * 256] = src[tid + k * 256];
    }
    __syncthreads();

    // cb_sq: 8 threads, 512 FMAs each (trivial)
    if (tid < 8) {
        const float* r = cbs + tid * D_DIM;
        float s = 0.f;
        for (int d = 0; d < D_DIM; ++d) s = fmaf(r[d], r[d], s);
        cb_sq[c0 + tid] = s;
    }

    // S[k]: each thread owns 2 rows e of W, computes diff^2 contribution for
    // all 8 codes. LDS reads of cbs are wave-uniform -> broadcast (free).
    float part[8];
    #pragma unroll
    for (int c = 0; c < 8; ++c) part[c] = 0.f;

    for (int rep = 0; rep < 2; ++rep) {
        const int e = rep * 256 + tid;
        const float4* wrow = (const float4*)(W + (size_t)e * D_DIM);
        float acc[8];
        #pragma unroll
        for (int c = 0; c < 8; ++c) acc[c] = 0.f;
        for (int dq = 0; dq < D_DIM / 4; ++dq) {
            const float4 wv = wrow[dq];
            #pragma unroll
            for (int c = 0; c < 8; ++c) {
                const float4 cv = ((const float4*)(cbs + c * D_DIM))[dq];
                acc[c] += cv.x * wv.x + cv.y * wv.y + cv.z * wv.z + cv.w * wv.w;
            }
        }
        const float bias = pb[e];
        #pragma unroll
        for (int c = 0; c < 8; ++c) {
            const float diff = acc[c] + bias - cbs[c * D_DIM + e];
            part[c] = fmaf(diff, diff, part[c]);
        }
    }

    // reduce each code's partial across 256 threads
    for (int c = 0; c < 8; ++c) {
        __syncthreads();
        red[tid] = part[c];
        __syncthreads();
        for (int s = 128; s > 0; s >>= 1) {
            if (tid < s) red[tid] += red[tid + s];
            __syncthreads();
        }
        if (tid == 0) Sk[c0 + c] = red[0];
    }
}

// ---------------------------------------------------------------------------
// Kernel 2: fused means + distance GEMM + argmin + gather + loss.
// Grid 256 blocks (1/CU), 256 threads (4 waves). Block owns 128 rows,
// loops over 16 code-tiles of 128. 8x8 micro-tile per thread, BK=32,
// LDS double-buffer + register prefetch of next chunk.
// ---------------------------------------------------------------------------
__global__ __launch_bounds__(256, 1)
void cra_main_kernel(const float* __restrict__ ce,     // [B*L, 512] char embeddings
                     const float* __restrict__ cb,     // [2048, 512] codebook
                     const float* __restrict__ cb_sq,  // [2048]
                     const float* __restrict__ Sk,     // [2048]
                     float* __restrict__ out_idx,
                     float* __restrict__ out_emb,
                     float* __restrict__ out_loss)
{
    __shared__ float Abuf[2][BK * LDT];   // 33.8 KB  A_lds[kk][row] (transposed)
    __shared__ float Bbuf[2][BK * LDT];   // 33.8 KB  B_lds[kk][code]
    __shared__ unsigned s_best[BM];

    const int tid = threadIdx.x;
    const int tx = tid & 15;   // code group: codes tx*8 .. tx*8+7 (within tile)
    const int ty = tid >> 4;   // row  group: rows  ty*8 .. ty*8+7
    const int rowBase = blockIdx.x * BM;

    float bestVal[8];
    unsigned bestIdx[8];
    #pragma unroll
    for (int i = 0; i < 8; ++i) { bestVal[i] = 3.402823466e38f; bestIdx[i] = 0u; }

    // staging geometry: flat f = tid + k*256 covers (row 0..127) x (dq 0..7);
    // 8 consecutive lanes read 128 B contiguous per char row -> coalesced.
    int sr[4], sdq[4];
    #pragma unroll
    for (int k = 0; k < 4; ++k) { const int f = tid + k * 256; sr[k] = f >> 3; sdq[k] = f & 7; }

    float4 pa0[4], pa1[4], pbv[4];   // prefetch registers

    for (int kt = 0; kt < N_TILES; ++kt) {
        const int kBase = kt * BN;
        float acc[8][8];
        #pragma unroll
        for (int i = 0; i < 8; ++i)
            #pragma unroll
            for (int j = 0; j < 8; ++j) acc[i][j] = 0.f;

        // ---- prologue: load chunk 0, write LDS buf 0
        #pragma unroll
        for (int k = 0; k < 4; ++k) {
            const size_t arow = (size_t)(2 * (rowBase + sr[k])) * D_DIM + (size_t)(sdq[k] * 4);
            pa0[k] = *(const float4*)(ce + arow);
            pa1[k] = *(const float4*)(ce + arow + D_DIM);
            pbv[k] = *(const float4*)(cb + (size_t)(kBase + sr[k]) * D_DIM + (size_t)(sdq[k] * 4));
        }
        #pragma unroll
        for (int k = 0; k < 4; ++k) {
            const int kk0 = sdq[k] * 4, r = sr[k];
            Abuf[0][(kk0 + 0) * LDT + r] = 0.5f * (pa0[k].x + pa1[k].x);
            Abuf[0][(kk0 + 1) * LDT + r] = 0.5f * (pa0[k].y + pa1[k].y);
            Abuf[0][(kk0 + 2) * LDT + r] = 0.5f * (pa0[k].z + pa1[k].z);
            Abuf[0][(kk0 + 3) * LDT + r] = 0.5f * (pa0[k].w + pa1[k].w);
            Bbuf[0][(kk0 + 0) * LDT + r] = pbv[k].x;
            Bbuf[0][(kk0 + 1) * LDT + r] = pbv[k].y;
            Bbuf[0][(kk0 + 2) * LDT + r] = pbv[k].z;
            Bbuf[0][(kk0 + 3) * LDT + r] = pbv[k].w;
        }
        __syncthreads();

        for (int c = 0; c < D_CHUNKS; ++c) {
            const int cur = c & 1;
            if (c + 1 < D_CHUNKS) {   // prefetch next chunk into registers
                const int dBase = (c + 1) * BK;
                #pragma unroll
                for (int k = 0; k < 4; ++k) {
                    const size_t arow = (size_t)(2 * (rowBase + sr[k])) * D_DIM + (size_t)(dBase + sdq[k] * 4);
                    pa0[k] = *(const float4*)(ce + arow);
                    pa1[k] = *(const float4*)(ce + arow + D_DIM);
                    pbv[k] = *(const float4*)(cb + (size_t)(kBase + sr[k]) * D_DIM + (size_t)(dBase + sdq[k] * 4));
                }
            }
            // compute: 32 kk x 64 FMA, ds_read_b128 for a/b fragments
            #pragma unroll 4
            for (int kk = 0; kk < BK; ++kk) {
                const float4 a0 = *(const float4*)&Abuf[cur][kk * LDT + ty * 8];
                const float4 a1 = *(const float4*)&Abuf[cur][kk * LDT + ty * 8 + 4];
                const float4 b0 = *(const float4*)&Bbuf[cur][kk * LDT + tx * 8];
                const float4 b1 = *(const float4*)&Bbuf[cur][kk * LDT + tx * 8 + 4];
                const float av[8] = {a0.x, a0.y, a0.z, a0.w, a1.x, a1.y, a1.z, a1.w};
                const float bv[8] = {b0.x, b0.y, b0.z, b0.w, b1.x, b1.y, b1.z, b1.w};
                #pragma unroll
                for (int i = 0; i < 8; ++i)
                    #pragma unroll
                    for (int j = 0; j < 8; ++j)
                        acc[i][j] = fmaf(av[i], bv[j], acc[i][j]);
            }
            if (c + 1 < D_CHUNKS) {   // write prefetched chunk to the other buffer
                const int nb = (c + 1) & 1;
                #pragma unroll
                for (int k = 0; k < 4; ++k) {
                    const int kk0 = sdq[k] * 4, r = sr[k];
                    Abuf[nb][(kk0 + 0) * LDT + r] = 0.5f * (pa0[k].x + pa1[k].x);
                    Abuf[nb][(kk0 + 1) * LDT + r] = 0.5f * (pa0[k].y + pa1[k].y);
                    Abuf[nb][(kk0 + 2) * LDT + r] = 0.5f * (pa0[k].z + pa1[k].z);
                    Abuf[nb][(kk0 + 3) * LDT + r] = 0.5f * (pa0[k].w + pa1[k].w);
                    Bbuf[nb][(kk0 + 0) * LDT + r] = pbv[k].x;
                    Bbuf[nb][(kk0 + 1) * LDT + r] = pbv[k].y;
                    Bbuf[nb][(kk0 + 2) * LDT + r] = pbv[k].z;
                    Bbuf[nb][(kk0 + 3) * LDT + r] = pbv[k].w;
                }
            }
            __syncthreads();
        }

        // epilogue: d2 = cb_sq[k] - 2*dot; running argmin (ascending k, strict <
        // => numpy first-occurrence semantics)
        float qv[8];
        {
            const float4 q0 = *(const float4*)(cb_sq + kBase + tx * 8);
            const float4 q1 = *(const float4*)(cb_sq + kBase + tx * 8 + 4);
            qv[0] = q0.x; qv[1] = q0.y; qv[2] = q0.z; qv[3] = q0.w;
            qv[4] = q1.x; qv[5] = q1.y; qv[6] = q1.z; qv[7] = q1.w;
        }
        #pragma unroll
        for (int i = 0; i < 8; ++i) {
            #pragma unroll
            for (int j = 0; j < 8; ++j) {
                const float val = qv[j] - 2.0f * acc[i][j];
                if (val < bestVal[i]) {
                    bestVal[i] = val;
                    bestIdx[i] = (unsigned)(kBase + tx * 8 + j);
                }
            }
        }
    }

    // ---- cross-thread merge (per row, over the 16 tx groups) ----
    __syncthreads();
    float*    s_val  = (float*)Abuf;              // 128 x 16
    unsigned* s_idx  = (unsigned*)Bbuf;           // 128 x 16
    float*    s_loss = ((float*)Bbuf) + 2048;     // 128 (disjoint from s_idx)

    #pragma unroll
    for (int i = 0; i < 8; ++i) {
        const int r = ty * 8 + i;
        s_val[r * 16 + tx] = bestVal[i];
        s_idx[r * 16 + tx] = bestIdx[i];
    }
    __syncthreads();

    if (tid < BM) {
        float bv = s_val[tid * 16];
        unsigned bi = s_idx[tid * 16];
        #pragma unroll
        for (int t = 1; t < 16; ++t) {
            const float v = s_val[tid * 16 + t];
            const unsigned ii = s_idx[tid * 16 + t];
            if (v < bv || (v == bv && ii < bi)) { bv = v; bi = ii; }
        }
        s_best[tid] = bi;
        out_idx[rowBase + tid] = (float)bi;       // harness reads whole d_out as f32
        s_loss[tid] = Sk[bi];
    }
    __syncthreads();

    // loss partial: sum S[idx] over the block's 128 rows, one atomic per block
    for (int s = 64; s > 0; s >>= 1) {
        if (tid < s) s_loss[tid] += s_loss[tid + s];
        __syncthreads();
    }
    if (tid == 0)
        atomicAdd(out_loss, s_loss[0] * (1.0f / ((float)N_ROWS * (float)D_DIM)));

    // gather word embeddings: copy selected codebook rows (L2-hot reads)
    const float4* cb4  = (const float4*)cb;
    float4*       out4 = (float4*)out_emb;
    for (int j = tid; j < BM * (D_DIM / 4); j += 256) {
        const int r = j >> 7;          // row within block
        const int q = j & 127;         // float4 index within row
        out4[(size_t)(rowBase + r) * (D_DIM / 4) + q] =
            cb4[(size_t)s_best[r] * (D_DIM / 4) + q];
    }
}

// ---------------------------------------------------------------------------
extern "C" void kernel_launch(void* const* d_in, const int* in_sizes, int n_in,
                              void* d_out, int out_size, void* d_ws, size_t ws_size,
                              hipStream_t stream)
{
    // inputs: 0 char_tokens (unused by reference), 1 char_embeddings,
    //         2 word_codebook, 3 proj_w, 4 proj_b
    const float* ce = (const float*)d_in[1];
    const float* cb = (const float*)d_in[2];
    const float* W  = (const float*)d_in[3];
    const float* pb = (const float*)d_in[4];

    float* cb_sq = (float*)d_ws;          // 2048 f32
    float* Sk    = cb_sq + K_CODES;       // 2048 f32  (16 KB ws total)

    float* out_idx  = (float*)d_out;
    float* out_emb  = out_idx + N_ROWS;
    float* out_loss = out_emb + (size_t)N_ROWS * D_DIM;

    cra_stats_kernel<<<K_CODES / 8, 256, 0, stream>>>(cb, W, pb, cb_sq, Sk, out_loss);
    cra_main_kernel<<<N_ROWS / BM, 256, 0, stream>>>(ce, cb, cb_sq, Sk,
                                                     out_idx, out_emb, out_loss);
}

// Round 2
// 1259.772 us; speedup vs baseline: 1.0410x; 1.0410x over previous
//
#include <hip/hip_runtime.h>

// SimpleCRA: B=16 L=4096 D=512, codebook 2048x512, WORD_LEN=2.
// Outputs (concat f32): indices[32768], embeddings[32768*512], loss[1].
//
// Round 2 changes vs round 1 (1225 us main, VALUBusy 46.6%, occ 11.7%,
// LDS conflicts 1.18e8):
//  - BM 128->64, grid 256->512: 2 blocks/CU (51 KB LDS each) = 2 waves/SIMD.
//    Independent blocks overlap each other's barrier/staging stalls.
//  - B-fragment reads split tx*4 / 64+tx*4 (was tx*8): bank start 4tx%32
//    -> 2-way (free) instead of 4-way (1.58x).
//  - f32 vector math mandatory: bf16 MFMA error (~4e-3 rel) would flip argmins.

#define D_DIM    512
#define K_CODES  2048
#define N_ROWS   32768          // B * L / WORD_LEN
#define BM       64
#define BN       128
#define BK       32
#define LDTA     68             // padded LDS row stride for A (floats)
#define LDTB     132            // padded LDS row stride for B (floats)
#define N_TILES  (K_CODES / BN) // 16
#define D_CHUNKS (D_DIM / BK)   // 16

// ---------------------------------------------------------------------------
// Kernel 1: codebook stats. 256 blocks x 256 threads, 8 codes per block.
// cb_sq[k] = sum_d cb[k,d]^2
// S[k]     = sum_e (dot(cb[k,:], W[e,:]) + pb[e] - cb[k,e])^2
// Also zeroes the loss accumulator (d_out is poisoned 0xAA before every launch).
// ---------------------------------------------------------------------------
__global__ __launch_bounds__(256, 1)
void cra_stats_kernel(const float* __restrict__ cb,
                      const float* __restrict__ W,
                      const float* __restrict__ pb,
                      float* __restrict__ cb_sq,
                      float* __restrict__ Sk,
                      float* __restrict__ loss_out)
{
    __shared__ float cbs[8 * D_DIM];   // 16 KB: 8 codebook rows
    __shared__ float red[4 * 8];       // per-wave partials x 8 codes
    const int tid = threadIdx.x;
    const int c0  = blockIdx.x * 8;

    if (blockIdx.x == 0 && tid == 0) loss_out[0] = 0.0f;

    // stage 8 contiguous codebook rows, coalesced float4
    {
        const float4* src = (const float4*)(cb + (size_t)c0 * D_DIM);
        float4* dst = (float4*)cbs;
        #pragma unroll
        for (int k = 0; k < 4; ++k) dst[tid + k * 256] = src[tid + k * 256];
    }
    __syncthreads();

    // cb_sq: 8 threads, 512 FMAs each (trivial; diverges only in wave 0)
    if (tid < 8) {
        const float* r = cbs + tid * D_DIM;
        float s = 0.f;
        for (int d = 0; d < D_DIM; ++d) s = fmaf(r[d], r[d], s);
        cb_sq[c0 + tid] = s;
    }

    // S[k]: each thread owns 2 rows e of W; LDS reads of cbs broadcast.
    float part[8];
    #pragma unroll
    for (int c = 0; c < 8; ++c) part[c] = 0.f;

    for (int rep = 0; rep < 2; ++rep) {
        const int e = rep * 256 + tid;
        const float4* wrow = (const float4*)(W + (size_t)e * D_DIM);
        float acc[8];
        #pragma unroll
        for (int c = 0; c < 8; ++c) acc[c] = 0.f;
        for (int dq = 0; dq < D_DIM / 4; ++dq) {
            const float4 wv = wrow[dq];
            #pragma unroll
            for (int c = 0; c < 8; ++c) {
                const float4 cv = ((const float4*)(cbs + c * D_DIM))[dq];
                acc[c] += cv.x * wv.x + cv.y * wv.y + cv.z * wv.z + cv.w * wv.w;
            }
        }
        const float bias = pb[e];
        #pragma unroll
        for (int c = 0; c < 8; ++c) {
            const float diff = acc[c] + bias - cbs[c * D_DIM + e];
            part[c] = fmaf(diff, diff, part[c]);
        }
    }

    // wave-level shuffle reduce, then 4-partial sum per code
    #pragma unroll
    for (int c = 0; c < 8; ++c) {
        float v = part[c];
        #pragma unroll
        for (int off = 32; off > 0; off >>= 1) v += __shfl_down(v, off, 64);
        if ((tid & 63) == 0) red[(tid >> 6) * 8 + c] = v;
    }
    __syncthreads();
    if (tid < 8)
        Sk[c0 + tid] = red[0 * 8 + tid] + red[1 * 8 + tid] +
                       red[2 * 8 + tid] + red[3 * 8 + tid];
}

// ---------------------------------------------------------------------------
// Kernel 2: fused means + distance GEMM + argmin + gather + loss.
// Grid 512 blocks (2/CU), 256 threads (4 waves). Block owns 64 rows,
// loops over 16 code-tiles of 128. 4x8 micro-tile per thread, BK=32,
// LDS double-buffer + register prefetch of next chunk.
// ---------------------------------------------------------------------------
__global__ __launch_bounds__(256, 2)
void cra_main_kernel(const float* __restrict__ ce,     // [B*L, 512] char embeddings
                     const float* __restrict__ cb,     // [2048, 512] codebook
                     const float* __restrict__ cb_sq,  // [2048]
                     const float* __restrict__ Sk,     // [2048]
                     float* __restrict__ out_idx,
                     float* __restrict__ out_emb,
                     float* __restrict__ out_loss)
{
    __shared__ float Abuf[2][BK * LDTA];   // 17.4 KB  A_lds[kk][row] (transposed)
    __shared__ float Bbuf[2][BK * LDTB];   // 33.8 KB  B_lds[kk][code]
    __shared__ unsigned s_best[BM];

    const int tid = threadIdx.x;
    const int tx = tid & 15;   // code group: cols tx*4..+3 and 64+tx*4..+3
    const int ty = tid >> 4;   // row group: rows ty*4 .. ty*4+3
    const int rowBase = blockIdx.x * BM;

    // staging geometry: lane -> (base_r, dq); 8 lanes cover 128 B of one row.
    const int base_r = tid >> 3;   // 0..31
    const int dq     = tid & 7;    // float4 index within 32-float chunk

    float bestVal[4];
    unsigned bestIdx[4];
    #pragma unroll
    for (int i = 0; i < 4; ++i) { bestVal[i] = 3.402823466e38f; bestIdx[i] = 0u; }

    float4 pa0[2], pa1[2], pbv[4];   // prefetch registers

    for (int kt = 0; kt < N_TILES; ++kt) {
        const int kBase = kt * BN;
        float acc[4][8];
        #pragma unroll
        for (int i = 0; i < 4; ++i)
            #pragma unroll
            for (int j = 0; j < 8; ++j) acc[i][j] = 0.f;

        // ---- prologue: load chunk 0, write LDS buf 0
        #pragma unroll
        for (int m = 0; m < 2; ++m) {
            const size_t arow = (size_t)(2 * (rowBase + base_r + 32 * m)) * D_DIM + (size_t)(dq * 4);
            pa0[m] = *(const float4*)(ce + arow);
            pa1[m] = *(const float4*)(ce + arow + D_DIM);
        }
        #pragma unroll
        for (int k = 0; k < 4; ++k)
            pbv[k] = *(const float4*)(cb + (size_t)(kBase + 32 * k + base_r) * D_DIM + (size_t)(dq * 4));
        {
            const int kk0 = dq * 4;
            #pragma unroll
            for (int m = 0; m < 2; ++m) {
                const int r = base_r + 32 * m;
                Abuf[0][(kk0 + 0) * LDTA + r] = 0.5f * (pa0[m].x + pa1[m].x);
                Abuf[0][(kk0 + 1) * LDTA + r] = 0.5f * (pa0[m].y + pa1[m].y);
                Abuf[0][(kk0 + 2) * LDTA + r] = 0.5f * (pa0[m].z + pa1[m].z);
                Abuf[0][(kk0 + 3) * LDTA + r] = 0.5f * (pa0[m].w + pa1[m].w);
            }
            #pragma unroll
            for (int k = 0; k < 4; ++k) {
                const int r = base_r + 32 * k;
                Bbuf[0][(kk0 + 0) * LDTB + r] = pbv[k].x;
                Bbuf[0][(kk0 + 1) * LDTB + r] = pbv[k].y;
                Bbuf[0][(kk0 + 2) * LDTB + r] = pbv[k].z;
                Bbuf[0][(kk0 + 3) * LDTB + r] = pbv[k].w;
            }
        }
        __syncthreads();

        for (int c = 0; c < D_CHUNKS; ++c) {
            const int cur = c & 1;
            if (c + 1 < D_CHUNKS) {   // prefetch next chunk into registers
                const int dBase = (c + 1) * BK;
                #pragma unroll
                for (int m = 0; m < 2; ++m) {
                    const size_t arow = (size_t)(2 * (rowBase + base_r + 32 * m)) * D_DIM + (size_t)(dBase + dq * 4);
                    pa0[m] = *(const float4*)(ce + arow);
                    pa1[m] = *(const float4*)(ce + arow + D_DIM);
                }
                #pragma unroll
                for (int k = 0; k < 4; ++k)
                    pbv[k] = *(const float4*)(cb + (size_t)(kBase + 32 * k + base_r) * D_DIM + (size_t)(dBase + dq * 4));
            }
            // compute: 32 kk x 32 FMA; A read broadcast, B reads 2-way (free)
            #pragma unroll 4
            for (int kk = 0; kk < BK; ++kk) {
                const float4 a  = *(const float4*)&Abuf[cur][kk * LDTA + ty * 4];
                const float4 b0 = *(const float4*)&Bbuf[cur][kk * LDTB + tx * 4];
                const float4 b1 = *(const float4*)&Bbuf[cur][kk * LDTB + 64 + tx * 4];
                const float av[4] = {a.x, a.y, a.z, a.w};
                const float bv[8] = {b0.x, b0.y, b0.z, b0.w, b1.x, b1.y, b1.z, b1.w};
                #pragma unroll
                for (int i = 0; i < 4; ++i)
                    #pragma unroll
                    for (int j = 0; j < 8; ++j)
                        acc[i][j] = fmaf(av[i], bv[j], acc[i][j]);
            }
            if (c + 1 < D_CHUNKS) {   // write prefetched chunk to the other buffer
                const int nb = (c + 1) & 1;
                const int kk0 = dq * 4;
                #pragma unroll
                for (int m = 0; m < 2; ++m) {
                    const int r = base_r + 32 * m;
                    Abuf[nb][(kk0 + 0) * LDTA + r] = 0.5f * (pa0[m].x + pa1[m].x);
                    Abuf[nb][(kk0 + 1) * LDTA + r] = 0.5f * (pa0[m].y + pa1[m].y);
                    Abuf[nb][(kk0 + 2) * LDTA + r] = 0.5f * (pa0[m].z + pa1[m].z);
                    Abuf[nb][(kk0 + 3) * LDTA + r] = 0.5f * (pa0[m].w + pa1[m].w);
                }
                #pragma unroll
                for (int k = 0; k < 4; ++k) {
                    const int r = base_r + 32 * k;
                    Bbuf[nb][(kk0 + 0) * LDTB + r] = pbv[k].x;
                    Bbuf[nb][(kk0 + 1) * LDTB + r] = pbv[k].y;
                    Bbuf[nb][(kk0 + 2) * LDTB + r] = pbv[k].z;
                    Bbuf[nb][(kk0 + 3) * LDTB + r] = pbv[k].w;
                }
            }
            __syncthreads();
        }

        // epilogue: d2 = cb_sq[k] - 2*dot; running argmin (ascending k, strict <
        // => numpy first-occurrence semantics; col order j=0..7 is ascending)
        float qv[8];
        {
            const float4 q0 = *(const float4*)(cb_sq + kBase + tx * 4);
            const float4 q1 = *(const float4*)(cb_sq + kBase + 64 + tx * 4);
            qv[0] = q0.x; qv[1] = q0.y; qv[2] = q0.z; qv[3] = q0.w;
            qv[4] = q1.x; qv[5] = q1.y; qv[6] = q1.z; qv[7] = q1.w;
        }
        #pragma unroll
        for (int i = 0; i < 4; ++i) {
            #pragma unroll
            for (int j = 0; j < 8; ++j) {
                const float val = qv[j] - 2.0f * acc[i][j];
                const unsigned col = (unsigned)(kBase + (j < 4 ? tx * 4 + j : 64 + tx * 4 + (j - 4)));
                if (val < bestVal[i]) { bestVal[i] = val; bestIdx[i] = col; }
            }
        }
    }

    // ---- cross-thread merge (per row, over the 16 tx groups) ----
    __syncthreads();
    float*    s_val  = (float*)Abuf;              // 64 x 16
    unsigned* s_idx  = (unsigned*)Bbuf;           // 64 x 16
    float*    s_loss = ((float*)Bbuf) + 1024;     // 64 (disjoint from s_idx)

    #pragma unroll
    for (int i = 0; i < 4; ++i) {
        const int r = ty * 4 + i;
        s_val[r * 16 + tx] = bestVal[i];
        s_idx[r * 16 + tx] = bestIdx[i];
    }
    __syncthreads();

    if (tid < BM) {
        float bv = s_val[tid * 16];
        unsigned bi = s_idx[tid * 16];
        #pragma unroll
        for (int t = 1; t < 16; ++t) {
            const float v = s_val[tid * 16 + t];
            const unsigned ii = s_idx[tid * 16 + t];
            if (v < bv || (v == bv && ii < bi)) { bv = v; bi = ii; }
        }
        s_best[tid] = bi;
        out_idx[rowBase + tid] = (float)bi;       // harness reads whole d_out as f32
        s_loss[tid] = Sk[bi];
    }
    __syncthreads();

    // loss partial: sum S[idx] over the block's 64 rows, one atomic per block
    for (int s = 32; s > 0; s >>= 1) {
        if (tid < s) s_loss[tid] += s_loss[tid + s];
        __syncthreads();
    }
    if (tid == 0)
        atomicAdd(out_loss, s_loss[0] * (1.0f / ((float)N_ROWS * (float)D_DIM)));

    // gather word embeddings: copy selected codebook rows (L2-hot reads)
    const float4* cb4  = (const float4*)cb;
    float4*       out4 = (float4*)out_emb;
    for (int j = tid; j < BM * (D_DIM / 4); j += 256) {
        const int r = j >> 7;          // row within block
        const int q = j & 127;         // float4 index within row
        out4[(size_t)(rowBase + r) * (D_DIM / 4) + q] =
            cb4[(size_t)s_best[r] * (D_DIM / 4) + q];
    }
}

// ---------------------------------------------------------------------------
extern "C" void kernel_launch(void* const* d_in, const int* in_sizes, int n_in,
                              void* d_out, int out_size, void* d_ws, size_t ws_size,
                              hipStream_t stream)
{
    // inputs: 0 char_tokens (unused by reference), 1 char_embeddings,
    //         2 word_codebook, 3 proj_w, 4 proj_b
    const float* ce = (const float*)d_in[1];
    const float* cb = (const float*)d_in[2];
    const float* W  = (const float*)d_in[3];
    const float* pb = (const float*)d_in[4];

    float* cb_sq = (float*)d_ws;          // 2048 f32
    float* Sk    = cb_sq + K_CODES;       // 2048 f32  (16 KB ws total)

    float* out_idx  = (float*)d_out;
    float* out_emb  = out_idx + N_ROWS;
    float* out_loss = out_emb + (size_t)N_ROWS * D_DIM;

    cra_stats_kernel<<<K_CODES / 8, 256, 0, stream>>>(cb, W, pb, cb_sq, Sk, out_loss);
    cra_main_kernel<<<N_ROWS / BM, 256, 0, stream>>>(ce, cb, cb_sq, Sk,
                                                     out_idx, out_emb, out_loss);
}

// Round 3
// 957.397 us; speedup vs baseline: 1.3698x; 1.3158x over previous
//
#include <hip/hip_runtime.h>

// SimpleCRA round 3: split-bf16 MFMA distance GEMM + exact-f32 tie recheck.
//
// score[r][k] = cb_sq[k] - 2*dot(mean_r, cb_k). dot computed as
//   ah*bh + al*bh + ah*bl   (a = ah + al bf16 split; residual al*bl ~5e-8)
// via 3 chained mfma_f32_16x16x32_bf16 passes into one f32 accumulator.
// Rows whose (best2-best1) < 1e-5 (expected ~180) get an exact f32 recheck
// of the top-2 candidates (true argmin outside approx-top-2: P~1e-5).
//
// Pipeline: pack_stats -> gemm (4096 blocks) -> merge -> gather -> recheck.
// Per-(row,colblock) reduction scratch (8 MB) lives in the emb output region
// (written only later by gather). ws usage ~4.6 MB.

#define D_DIM    512
#define K_CODES  2048
#define N_ROWS   32768
#define EPS_GAP  1e-5f
#define LOSS_SCALE (1.0f / 16777216.0f)   // 1/(N_ROWS*D_DIM)
#define LDT      40                        // LDS k-stride (shorts): 80 B, 16B-aligned, 2-way max

typedef __attribute__((ext_vector_type(8))) short short8;   // 8 bf16 (4 VGPR)
typedef __attribute__((ext_vector_type(4))) float f32x4;    // MFMA C/D

__device__ inline unsigned short f32_bf16(float f) {        // RNE truncate
    unsigned u = __float_as_uint(f);
    u += 0x7FFFu + ((u >> 16) & 1u);
    return (unsigned short)(u >> 16);
}
__device__ inline float bf16_f32(unsigned short h) { return __uint_as_float(((unsigned)h) << 16); }

// insert candidate into sorted-2 list ordered by (val, idx) — total order,
// merge-order independent; matches numpy first-occurrence argmin.
__device__ inline void merge_cand(float s, int idx, float& v1, int& i1, float& v2, int& i2) {
    if (s < v1 || (s == v1 && idx < i1)) { v2 = v1; i2 = i1; v1 = s; i1 = idx; }
    else if (s < v2 || (s == v2 && idx < i2)) { v2 = s; i2 = idx; }
}

// ---------------------------------------------------------------------------
// Kernel 1: pack B panels (bh|bl per code row) + cb_sq + S[k] + zero loss/ctr.
// 256 blocks x 256 threads, 8 codes per block (R2-proven structure).
// ---------------------------------------------------------------------------
__global__ __launch_bounds__(256, 1)
void cra_pack_stats(const float* __restrict__ cb,
                    const float* __restrict__ W,
                    const float* __restrict__ pb,
                    unsigned short* __restrict__ wsB,   // [2048][1024]: [0..511]=bh, [512..1023]=bl
                    float* __restrict__ cb_sq,
                    float* __restrict__ Sk,
                    float* __restrict__ loss_out,
                    int* __restrict__ counter)
{
    __shared__ float cbs[8 * D_DIM];
    __shared__ float red[4 * 8];
    const int tid = threadIdx.x;
    const int c0  = blockIdx.x * 8;

    if (blockIdx.x == 0 && tid == 0) { loss_out[0] = 0.0f; counter[0] = 0; }

    {   // stage 8 codebook rows
        const float4* src = (const float4*)(cb + (size_t)c0 * D_DIM);
        float4* dst = (float4*)cbs;
        #pragma unroll
        for (int k = 0; k < 4; ++k) dst[tid + k * 256] = src[tid + k * 256];
    }
    __syncthreads();

    if (tid < 8) {
        const float* r = cbs + tid * D_DIM;
        float s = 0.f;
        for (int d = 0; d < D_DIM; ++d) s = fmaf(r[d], r[d], s);
        cb_sq[c0 + tid] = s;
    }

    {   // pack bf16 hi/lo: 16 elems per thread
        const int row = tid >> 5;            // 0..7
        const int off = (tid & 31) * 16;     // 0..496
        short8 h[2], l[2];
        #pragma unroll
        for (int g = 0; g < 2; ++g)
            #pragma unroll
            for (int e = 0; e < 8; ++e) {
                float f = cbs[row * D_DIM + off + g * 8 + e];
                unsigned short hi = f32_bf16(f);
                h[g][e] = (short)hi;
                l[g][e] = (short)f32_bf16(f - bf16_f32(hi));
            }
        unsigned short* dst = wsB + (size_t)(c0 + row) * 1024 + off;
        *(short8*)(dst)       = h[0];
        *(short8*)(dst + 8)   = h[1];
        *(short8*)(dst + 512) = l[0];
        *(short8*)(dst + 520) = l[1];
    }

    // S[k] = ||cb[k]@W^T + pb - cb[k]||^2 : thread owns 2 rows e of W
    float part[8];
    #pragma unroll
    for (int c = 0; c < 8; ++c) part[c] = 0.f;
    for (int rep = 0; rep < 2; ++rep) {
        const int e = rep * 256 + tid;
        const float4* wrow = (const float4*)(W + (size_t)e * D_DIM);
        float acc[8];
        #pragma unroll
        for (int c = 0; c < 8; ++c) acc[c] = 0.f;
        for (int dq = 0; dq < D_DIM / 4; ++dq) {
            const float4 wv = wrow[dq];
            #pragma unroll
            for (int c = 0; c < 8; ++c) {
                const float4 cv = ((const float4*)(cbs + c * D_DIM))[dq];
                acc[c] += cv.x * wv.x + cv.y * wv.y + cv.z * wv.z + cv.w * wv.w;
            }
        }
        const float bias = pb[e];
        #pragma unroll
        for (int c = 0; c < 8; ++c) {
            const float diff = acc[c] + bias - cbs[c * D_DIM + e];
            part[c] = fmaf(diff, diff, part[c]);
        }
    }
    #pragma unroll
    for (int c = 0; c < 8; ++c) {
        float v = part[c];
        #pragma unroll
        for (int off = 32; off > 0; off >>= 1) v += __shfl_down(v, off, 64);
        if ((tid & 63) == 0) red[(tid >> 6) * 8 + c] = v;
    }
    __syncthreads();
    if (tid < 8)
        Sk[c0 + tid] = red[0 * 8 + tid] + red[1 * 8 + tid] +
                       red[2 * 8 + tid] + red[3 * 8 + tid];
}

// ---------------------------------------------------------------------------
// Kernel 2: split-bf16 MFMA GEMM + per-(row,colblock) top-2 reduction.
// Grid 4096 = 256 row-blocks x 16 col-blocks (colb = bid&15 so the 16 blocks
// sharing an A-slab are dispatched together -> L2/L3 reuse of ce).
// Block: 256 thr = 4 waves, tile 128x128, wave quadrant 64x64 = 4x4 MFMA tiles.
// K-loop: 16 chunks of KC=32; per chunk 3 passes (Ah*Bh, Al*Bh, Ah*Bl).
// ---------------------------------------------------------------------------
__global__ __launch_bounds__(256, 2)
void cra_gemm(const float* __restrict__ ce,
              const unsigned short* __restrict__ wsB,
              const float* __restrict__ cb_sq,
              float4* __restrict__ wsRed)           // [32768][16] {v1,i1,v2,i2}
{
    __shared__ short sMem[4 * 128 * LDT];           // 40 KB
    short* sAh = sMem;
    short* sAl = sMem + 128 * LDT;
    short* sBh = sMem + 2 * 128 * LDT;
    short* sBl = sMem + 3 * 128 * LDT;

    const int tid  = threadIdx.x;
    const int colb = blockIdx.x & 15;
    const int mb   = blockIdx.x >> 4;
    const int rowBase = mb * 128;
    const int colBase = colb * 128;
    const int lane = tid & 63;
    const int w    = tid >> 6;
    const int wr     = (w & 1) * 64;     // wave row offset
    const int wcHalf = (w >> 1);
    const int wc     = wcHalf * 64;      // wave col offset
    const int cid  = lane & 15;
    const int quad = lane >> 4;

    f32x4 acc[4][4];
    #pragma unroll
    for (int i = 0; i < 4; ++i)
        #pragma unroll
        for (int j = 0; j < 4; ++j) acc[i][j] = (f32x4)(0.f);

    // staging: thread -> (row srow, k-half skh); 2 threads cover a 32-k row seg
    const int srow = tid >> 1;
    const int skh  = (tid & 1) * 16;
    const float* a0p = ce + (size_t)(2 * (rowBase + srow)) * D_DIM + skh;
    const float* a1p = a0p + D_DIM;
    const unsigned short* bp = wsB + (size_t)(colBase + srow) * 1024 + skh;

    float4 pA0[4], pA1[4];
    short8 pBh0, pBh1, pBl0, pBl1;

    // prologue: prefetch chunk 0
    #pragma unroll
    for (int q = 0; q < 4; ++q) {
        pA0[q] = *(const float4*)(a0p + q * 4);
        pA1[q] = *(const float4*)(a1p + q * 4);
    }
    pBh0 = *(const short8*)(bp);
    pBh1 = *(const short8*)(bp + 8);
    pBl0 = *(const short8*)(bp + 512);
    pBl1 = *(const short8*)(bp + 520);

    #pragma unroll 1
    for (int c = 0; c < 16; ++c) {
        {   // mean + split + LDS write (chunk c, from prefetch regs)
            float m[16];
            #pragma unroll
            for (int q = 0; q < 4; ++q) {
                m[q * 4 + 0] = 0.5f * (pA0[q].x + pA1[q].x);
                m[q * 4 + 1] = 0.5f * (pA0[q].y + pA1[q].y);
                m[q * 4 + 2] = 0.5f * (pA0[q].z + pA1[q].z);
                m[q * 4 + 3] = 0.5f * (pA0[q].w + pA1[q].w);
            }
            short8 h[2], l[2];
            #pragma unroll
            for (int g = 0; g < 2; ++g)
                #pragma unroll
                for (int e = 0; e < 8; ++e) {
                    float f = m[g * 8 + e];
                    unsigned short hi = f32_bf16(f);
                    h[g][e] = (short)hi;
                    l[g][e] = (short)f32_bf16(f - bf16_f32(hi));
                }
            *(short8*)&sAh[srow * LDT + skh]     = h[0];
            *(short8*)&sAh[srow * LDT + skh + 8] = h[1];
            *(short8*)&sAl[srow * LDT + skh]     = l[0];
            *(short8*)&sAl[srow * LDT + skh + 8] = l[1];
            *(short8*)&sBh[srow * LDT + skh]     = pBh0;
            *(short8*)&sBh[srow * LDT + skh + 8] = pBh1;
            *(short8*)&sBl[srow * LDT + skh]     = pBl0;
            *(short8*)&sBl[srow * LDT + skh + 8] = pBl1;
        }
        __syncthreads();

        if (c < 15) {   // prefetch chunk c+1 (latency hidden by MFMA below)
            const int k0 = (c + 1) * 32;
            #pragma unroll
            for (int q = 0; q < 4; ++q) {
                pA0[q] = *(const float4*)(a0p + k0 + q * 4);
                pA1[q] = *(const float4*)(a1p + k0 + q * 4);
            }
            pBh0 = *(const short8*)(bp + k0);
            pBh1 = *(const short8*)(bp + k0 + 8);
            pBl0 = *(const short8*)(bp + k0 + 512);
            pBl1 = *(const short8*)(bp + k0 + 520);
        }

        // ---- 3 MFMA passes; frag layout [m|n = lane&15][k = quad*8 + j]
        short8 aF[4], bF[4];
        #pragma unroll
        for (int mi = 0; mi < 4; ++mi) aF[mi] = *(const short8*)&sAh[(wr + mi * 16 + cid) * LDT + quad * 8];
        #pragma unroll
        for (int ni = 0; ni < 4; ++ni) bF[ni] = *(const short8*)&sBh[(wc + ni * 16 + cid) * LDT + quad * 8];
        #pragma unroll
        for (int mi = 0; mi < 4; ++mi)
            #pragma unroll
            for (int ni = 0; ni < 4; ++ni)
                acc[mi][ni] = __builtin_amdgcn_mfma_f32_16x16x32_bf16(aF[mi], bF[ni], acc[mi][ni], 0, 0, 0);
        #pragma unroll
        for (int mi = 0; mi < 4; ++mi) aF[mi] = *(const short8*)&sAl[(wr + mi * 16 + cid) * LDT + quad * 8];
        #pragma unroll
        for (int mi = 0; mi < 4; ++mi)
            #pragma unroll
            for (int ni = 0; ni < 4; ++ni)
                acc[mi][ni] = __builtin_amdgcn_mfma_f32_16x16x32_bf16(aF[mi], bF[ni], acc[mi][ni], 0, 0, 0);
        #pragma unroll
        for (int mi = 0; mi < 4; ++mi) aF[mi] = *(const short8*)&sAh[(wr + mi * 16 + cid) * LDT + quad * 8];
        #pragma unroll
        for (int ni = 0; ni < 4; ++ni) bF[ni] = *(const short8*)&sBl[(wc + ni * 16 + cid) * LDT + quad * 8];
        #pragma unroll
        for (int mi = 0; mi < 4; ++mi)
            #pragma unroll
            for (int ni = 0; ni < 4; ++ni)
                acc[mi][ni] = __builtin_amdgcn_mfma_f32_16x16x32_bf16(aF[mi], bF[ni], acc[mi][ni], 0, 0, 0);
        __syncthreads();
    }

    // ---- epilogue: score + top-2; C/D layout col=lane&15, row=quad*4+reg
    float cq[4];
    #pragma unroll
    for (int ni = 0; ni < 4; ++ni) cq[ni] = cb_sq[colBase + wc + ni * 16 + cid];

    float4* sRed = (float4*)sMem;    // [row 128][half 2][slot 4], 16 KB
    #pragma unroll
    for (int mi = 0; mi < 4; ++mi) {
        #pragma unroll
        for (int reg = 0; reg < 4; ++reg) {
            float v1 = 3.4e38f, v2 = 3.4e38f;
            int   i1 = 0x7FFFFFFF, i2 = 0x7FFFFFFF;
            #pragma unroll
            for (int ni = 0; ni < 4; ++ni) {
                float s = fmaf(-2.0f, acc[mi][ni][reg], cq[ni]);
                merge_cand(s, colBase + wc + ni * 16 + cid, v1, i1, v2, i2);
            }
            // reduce over 4-lane col groups (xor 1,2 within the 16 cols)
            #pragma unroll
            for (int d = 1; d <= 2; d <<= 1) {
                float ov1 = __shfl_xor(v1, d); int oi1 = __shfl_xor(i1, d);
                float ov2 = __shfl_xor(v2, d); int oi2 = __shfl_xor(i2, d);
                merge_cand(ov1, oi1, v1, i1, v2, i2);
                merge_cand(ov2, oi2, v1, i1, v2, i2);
            }
            if ((cid & 3) == 0) {
                int row = wr + mi * 16 + quad * 4 + reg;
                sRed[(row * 2 + wcHalf) * 4 + (cid >> 2)] =
                    make_float4(v1, __int_as_float(i1), v2, __int_as_float(i2));
            }
        }
    }
    __syncthreads();
    if (tid < 128) {
        float v1 = 3.4e38f, v2 = 3.4e38f;
        int   i1 = 0x7FFFFFFF, i2 = 0x7FFFFFFF;
        #pragma unroll
        for (int e = 0; e < 8; ++e) {
            float4 t = sRed[tid * 8 + e];
            merge_cand(t.x, __float_as_int(t.y), v1, i1, v2, i2);
            merge_cand(t.z, __float_as_int(t.w), v1, i1, v2, i2);
        }
        wsRed[(size_t)(rowBase + tid) * 16 + colb] =
            make_float4(v1, __int_as_float(i1), v2, __int_as_float(i2));
    }
}

// ---------------------------------------------------------------------------
// Kernel 3: merge 16 colblock results per row; write idx, flag ties, loss.
// ---------------------------------------------------------------------------
__global__ __launch_bounds__(256, 1)
void cra_merge(const float4* __restrict__ wsRed,
               const float* __restrict__ Sk,
               float* __restrict__ out_idx,
               float* __restrict__ out_loss,
               int* __restrict__ counter,
               int* __restrict__ flagRow,
               int2* __restrict__ flagI)
{
    __shared__ float sl[256];
    const int tid = threadIdx.x;
    const int r = blockIdx.x * 256 + tid;
    float v1 = 3.4e38f, v2 = 3.4e38f;
    int   i1 = 0x7FFFFFFF, i2 = 0x7FFFFFFF;
    #pragma unroll 4
    for (int cbk = 0; cbk < 16; ++cbk) {
        float4 t = wsRed[(size_t)r * 16 + cbk];
        merge_cand(t.x, __float_as_int(t.y), v1, i1, v2, i2);
        merge_cand(t.z, __float_as_int(t.w), v1, i1, v2, i2);
    }
    out_idx[r] = (float)i1;
    if (v2 - v1 < EPS_GAP) {
        int slot = atomicAdd(counter, 1);
        flagRow[slot] = r;
        flagI[slot] = make_int2(i1, i2);
    }
    sl[tid] = Sk[i1];
    __syncthreads();
    for (int s = 128; s > 0; s >>= 1) { if (tid < s) sl[tid] += sl[tid + s]; __syncthreads(); }
    if (tid == 0) atomicAdd(out_loss, sl[0] * LOSS_SCALE);
}

// ---------------------------------------------------------------------------
// Kernel 4: gather embeddings (overwrites the wsRed scratch region).
// ---------------------------------------------------------------------------
__global__ __launch_bounds__(256, 1)
void cra_gather(const float* __restrict__ out_idx,
                const float4* __restrict__ cb4,
                float4* __restrict__ out4)
{
    __shared__ int sidx[128];
    const int tid = threadIdx.x;
    const int rb = blockIdx.x * 128;
    if (tid < 128) sidx[tid] = (int)out_idx[rb + tid];
    __syncthreads();
    for (int j = tid; j < 128 * 128; j += 256) {
        int row = j >> 7, q = j & 127;
        out4[(size_t)(rb + row) * 128 + q] = cb4[(size_t)sidx[row] * 128 + q];
    }
}

// ---------------------------------------------------------------------------
// Kernel 5: exact-f32 recheck of flagged rows' top-2 candidates; fix up
// idx / emb / loss where the winner changes.
// ---------------------------------------------------------------------------
__global__ __launch_bounds__(256, 1)
void cra_recheck(const float* __restrict__ ce,
                 const float* __restrict__ cb,
                 const float* __restrict__ cb_sq,
                 const float* __restrict__ Sk,
                 const int* __restrict__ counter,
                 const int* __restrict__ flagRow,
                 const int2* __restrict__ flagI,
                 float* __restrict__ out_idx,
                 float4* __restrict__ out4,
                 float* __restrict__ out_loss,
                 const float4* __restrict__ cb4)
{
    __shared__ float rp[8];
    __shared__ int swin;
    const int tid = threadIdx.x;
    const int n = counter[0];
    for (int f = blockIdx.x; f < n; f += 64) {
        const int row = flagRow[f];
        const int2 ii = flagI[f];
        const int d0 = tid * 2;
        float2 x0 = *(const float2*)(ce + (size_t)(2 * row) * D_DIM + d0);
        float2 x1 = *(const float2*)(ce + (size_t)(2 * row) * D_DIM + D_DIM + d0);
        float m0 = 0.5f * (x0.x + x1.x), m1 = 0.5f * (x0.y + x1.y);
        const float* c1 = cb + (size_t)ii.x * D_DIM + d0;
        const float* c2 = cb + (size_t)ii.y * D_DIM + d0;
        float p1 = fmaf(m0, c1[0], m1 * c1[1]);
        float p2 = fmaf(m0, c2[0], m1 * c2[1]);
        #pragma unroll
        for (int off = 32; off > 0; off >>= 1) {
            p1 += __shfl_down(p1, off, 64);
            p2 += __shfl_down(p2, off, 64);
        }
        if ((tid & 63) == 0) { rp[(tid >> 6) * 2] = p1; rp[(tid >> 6) * 2 + 1] = p2; }
        __syncthreads();
        if (tid == 0) {
            float dot1 = rp[0] + rp[2] + rp[4] + rp[6];
            float dot2 = rp[1] + rp[3] + rp[5] + rp[7];
            float s1 = cb_sq[ii.x] - 2.f * dot1;
            float s2 = cb_sq[ii.y] - 2.f * dot2;
            int win = (s2 < s1 || (s2 == s1 && ii.y < ii.x)) ? ii.y : ii.x;
            swin = win;
            if (win != ii.x) {
                out_idx[row] = (float)win;
                atomicAdd(out_loss, (Sk[win] - Sk[ii.x]) * LOSS_SCALE);
            }
        }
        __syncthreads();
        if (swin != ii.x) {
            for (int q = tid; q < 128; q += 256)
                out4[(size_t)row * 128 + q] = cb4[(size_t)swin * 128 + q];
        }
        __syncthreads();
    }
}

// ---------------------------------------------------------------------------
extern "C" void kernel_launch(void* const* d_in, const int* in_sizes, int n_in,
                              void* d_out, int out_size, void* d_ws, size_t ws_size,
                              hipStream_t stream)
{
    // inputs: 0 char_tokens (unused), 1 char_embeddings, 2 word_codebook,
    //         3 proj_w, 4 proj_b
    const float* ce = (const float*)d_in[1];
    const float* cb = (const float*)d_in[2];
    const float* W  = (const float*)d_in[3];
    const float* pb = (const float*)d_in[4];

    char* ws = (char*)d_ws;                                  // ~4.6 MB used
    unsigned short* wsB = (unsigned short*)ws;               // 4 MB packed B
    float* cb_sq   = (float*)(ws + 4194304);
    float* Sk      = cb_sq + K_CODES;
    int*   flagRow = (int*)(ws + 4194304 + 16384);
    int2*  flagI   = (int2*)(ws + 4194304 + 16384 + 131072);
    int*   counter = (int*)(ws + 4194304 + 16384 + 131072 + 262144);

    float* out_idx  = (float*)d_out;
    float* out_emb  = out_idx + N_ROWS;
    float* out_loss = out_emb + (size_t)N_ROWS * D_DIM;
    float4* wsRed   = (float4*)out_emb;   // 8 MB scratch inside emb region (pre-gather)

    cra_pack_stats<<<256, 256, 0, stream>>>(cb, W, pb, wsB, cb_sq, Sk, out_loss, counter);
    cra_gemm<<<4096, 256, 0, stream>>>(ce, wsB, cb_sq, wsRed);
    cra_merge<<<128, 256, 0, stream>>>(wsRed, Sk, out_idx, out_loss, counter, flagRow, flagI);
    cra_gather<<<256, 256, 0, stream>>>(out_idx, (const float4*)cb, (float4*)out_emb);
    cra_recheck<<<64, 256, 0, stream>>>(ce, cb, cb_sq, Sk, counter, flagRow, flagI,
                                        out_idx, (float4*)out_emb, out_loss, (const float4*)cb);
}

// Round 4
// 950.808 us; speedup vs baseline: 1.3793x; 1.0069x over previous
//
#include <hip/hip_runtime.h>

// SimpleCRA round 4: coalesced staging + global_load_lds B-DMA + BN=256.
// score[r][k] = cb_sq[k] - 2*dot(mean_r, cb_k), dot via 3-pass split-bf16 MFMA
// (ah*bh + al*bh + ah*bl, truncation split; residual ~2e-7 << EPS 1e-5).
// Tie rows (gap < EPS) exactly rechecked on top-2 candidates.

#define D_DIM    512
#define K_CODES  2048
#define N_ROWS   32768
#define EPS_GAP  1e-5f
#define LOSS_SCALE (1.0f / 16777216.0f)   // 1/(N_ROWS*D_DIM)

typedef __attribute__((ext_vector_type(8))) short short8;   // 8 bf16 (4 VGPR)
typedef __attribute__((ext_vector_type(4))) float f32x4;    // MFMA C/D

__device__ __forceinline__ void split_bf16(float f, unsigned short& h, unsigned short& l) {
    unsigned u = __float_as_uint(f);
    h = (unsigned short)(u >> 16);                       // truncation split
    float hr = __uint_as_float(u & 0xFFFF0000u);
    l = (unsigned short)(__float_as_uint(f - hr) >> 16);
}

// async global->LDS DMA, 16 B/lane; lds ptr wave-uniform, HW adds lane*16.
__device__ __forceinline__ void dma16(const void* g, void* l) {
    __builtin_amdgcn_global_load_lds(
        (const __attribute__((address_space(1))) unsigned int*)g,
        (__attribute__((address_space(3))) unsigned int*)l, 16, 0, 0);
}

// insert candidate into sorted-2 list ordered by (val, idx) — total order,
// merge-order independent; matches numpy first-occurrence argmin.
__device__ __forceinline__ void merge_cand(float s, int idx, float& v1, int& i1, float& v2, int& i2) {
    if (s < v1 || (s == v1 && idx < i1)) { v2 = v1; i2 = i1; v1 = s; i1 = idx; }
    else if (s < v2 || (s == v2 && idx < i2)) { v2 = s; i2 = idx; }
}

// ---------------------------------------------------------------------------
// Kernel 1: pack B chunk-images (LDS-image order: [colb][chunk][row 256][32
// shorts]) for Bh/Bl + cb_sq. 64 blocks x 256 thr, 32 codes each.
// ---------------------------------------------------------------------------
__global__ __launch_bounds__(256, 1)
void cra_pack(const float* __restrict__ cb,
              unsigned short* __restrict__ wsBh,
              unsigned short* __restrict__ wsBl,
              float* __restrict__ cb_sq)
{
    __shared__ float cbs[32 * D_DIM];    // 64 KB
    const int tid = threadIdx.x;
    const int c0  = blockIdx.x * 32;

    {   // stage 32 codebook rows, coalesced float4
        const float4* src = (const float4*)(cb + (size_t)c0 * D_DIM);
        float4* dst = (float4*)cbs;
        #pragma unroll
        for (int k = 0; k < 16; ++k) dst[tid + k * 256] = src[tid + k * 256];
    }
    __syncthreads();

    if (tid < 32) {
        const float* r = cbs + tid * D_DIM;
        float s = 0.f;
        for (int d = 0; d < D_DIM; ++d) s = fmaf(r[d], r[d], s);
        cb_sq[c0 + tid] = s;
    }

    // pack: thread owns row (tid>>3), elems d0..d0+63
    const int row = tid >> 3;
    const int k   = c0 + row;
    const int colb = k >> 8;            // 0..7
    const int pr   = k & 255;
    const int d0   = (tid & 7) * 64;
    #pragma unroll
    for (int g = 0; g < 8; ++g) {
        const int d = d0 + g * 8;
        const int cchunk = d >> 5;
        const int s = d & 31;
        short8 h8, l8;
        #pragma unroll
        for (int e = 0; e < 8; ++e) {
            unsigned short hh, ll;
            split_bf16(cbs[row * D_DIM + d + e], hh, ll);
            h8[e] = (short)hh; l8[e] = (short)ll;
        }
        const size_t off = (size_t)colb * 131072 + cchunk * 8192 + pr * 32 + s;
        *(short8*)(wsBh + off) = h8;
        *(short8*)(wsBl + off) = l8;
    }
}

// ---------------------------------------------------------------------------
// Kernel 2: Sk[k] = ||cb[k]@W^T + pb - cb[k]||^2, atomically accumulated
// (Sk pre-zeroed by memset). 256 blocks = 64 code-blocks x 4 e-blocks.
// ---------------------------------------------------------------------------
__global__ __launch_bounds__(256, 1)
void cra_proj(const float* __restrict__ cb,
              const float* __restrict__ W,
              const float* __restrict__ pb,
              float* __restrict__ Sk)
{
    __shared__ float cbs[32 * D_DIM];    // 64 KB
    __shared__ float red[4 * 32];
    const int tid = threadIdx.x;
    const int cblock = blockIdx.x >> 2;
    const int eb     = blockIdx.x & 3;
    const int c0 = cblock * 32;

    {
        const float4* src = (const float4*)(cb + (size_t)c0 * D_DIM);
        float4* dst = (float4*)cbs;
        #pragma unroll
        for (int k = 0; k < 16; ++k) dst[tid + k * 256] = src[tid + k * 256];
    }
    __syncthreads();

    const int e  = eb * 128 + (tid >> 1);
    const int dh = (tid & 1) * 256;      // half of D owned by this lane
    float acc[32];
    #pragma unroll
    for (int c = 0; c < 32; ++c) acc[c] = 0.f;
    const float4* wrow = (const float4*)(W + (size_t)e * D_DIM + dh);
    for (int dq = 0; dq < 64; ++dq) {
        const float4 wv = wrow[dq];
        #pragma unroll
        for (int c = 0; c < 32; ++c) {
            const float4 cv = *(const float4*)&cbs[c * D_DIM + dh + dq * 4];
            acc[c] += cv.x * wv.x + cv.y * wv.y + cv.z * wv.z + cv.w * wv.w;
        }
    }
    const float bias = pb[e];
    const int w = tid >> 6;
    #pragma unroll
    for (int c = 0; c < 32; ++c) {
        const float full = acc[c] + __shfl_xor(acc[c], 1);   // combine the two D-halves
        const float diff = full + bias - cbs[c * D_DIM + e];
        float v = (tid & 1) ? 0.f : diff * diff;
        #pragma unroll
        for (int off = 32; off > 0; off >>= 1) v += __shfl_down(v, off, 64);
        if ((tid & 63) == 0) red[w * 32 + c] = v;
    }
    __syncthreads();
    if (tid < 32)
        atomicAdd(&Sk[c0 + tid],
                  red[tid] + red[32 + tid] + red[64 + tid] + red[96 + tid]);
}

// ---------------------------------------------------------------------------
// Kernel 3: split-bf16 MFMA GEMM, tile 128x256, 512 thr (8 waves, 64x64 each),
// 2 blocks/CU. A: coalesced f32 loads + in-kernel split; B: global_load_lds
// DMA from pre-packed images. XCD-grouped swizzle: 8 colbs of one mb share an
// XCD so the A-slab stays L2-local.
// ---------------------------------------------------------------------------
__global__ __launch_bounds__(512, 4)
void cra_gemm(const float* __restrict__ ce,
              const unsigned short* __restrict__ wsBh,
              const unsigned short* __restrict__ wsBl,
              const float* __restrict__ cb_sq,
              float4* __restrict__ wsRed)           // [32768][8] {v1,i1,v2,i2}
{
    __shared__ short sMem[24576];        // 48 KB: Ah|Al (4096 ea) Bh|Bl (8192 ea)
    short* sAh = sMem;
    short* sAl = sMem + 4096;
    short* sBh = sMem + 8192;
    short* sBl = sMem + 16384;

    const int tid  = threadIdx.x;
    const int bid  = blockIdx.x;
    const int xcd  = bid & 7;
    const int slot = bid >> 3;           // 0..255
    const int mb   = xcd * 32 + (slot >> 3);
    const int colb = slot & 7;
    const int rowBase = mb * 128;
    const int colBase = colb * 256;

    const int lane = tid & 63;
    const int w    = tid >> 6;           // 0..7
    const int wr   = (w & 1) * 64;
    const int cw   = w >> 1;             // 0..3
    const int wc   = cw * 64;
    const int cid  = lane & 15;
    const int quad = lane >> 4;

    f32x4 acc[4][4];
    #pragma unroll
    for (int i = 0; i < 4; ++i)
        #pragma unroll
        for (int j = 0; j < 4; ++j) acc[i][j] = (f32x4)(0.f);

    // A staging: thread -> (row, 8-elem span); 4 lanes = 128 B contiguous/row.
    const int srow = tid >> 2;           // 0..127
    const int sA   = (tid & 3) * 8;      // 0,8,16,24
    const float* a0p = ce + (size_t)(2 * (rowBase + srow)) * D_DIM + sA;
    const float* a1p = a0p + D_DIM;

    // B DMA bases (bytes): panel = colb*256KB, chunk = c*16KB, wave part 2KB.
    const char* gBh = (const char*)wsBh + ((size_t)colb << 18);
    const char* gBl = (const char*)wsBl + ((size_t)colb << 18);
    char* lBh = (char*)sBh + w * 2048;
    char* lBl = (char*)sBl + w * 2048;
    const int gwoff = w * 2048 + lane * 16;

    float4 pa[4];
    pa[0] = *(const float4*)(a0p);     pa[1] = *(const float4*)(a0p + 4);
    pa[2] = *(const float4*)(a1p);     pa[3] = *(const float4*)(a1p + 4);

    #pragma unroll 1
    for (int c = 0; c < 16; ++c) {
        // ---- issue B DMA for chunk c (latency covered by A convert below)
        {
            const char* gh = gBh + c * 16384 + gwoff;
            const char* gl = gBl + c * 16384 + gwoff;
            dma16(gh,        lBh);
            dma16(gh + 1024, lBh + 1024);
            dma16(gl,        lBl);
            dma16(gl + 1024, lBl + 1024);
        }
        // ---- stage A chunk c from prefetch regs: mean + split + LDS write
        {
            float m[8];
            m[0] = 0.5f * (pa[0].x + pa[2].x); m[1] = 0.5f * (pa[0].y + pa[2].y);
            m[2] = 0.5f * (pa[0].z + pa[2].z); m[3] = 0.5f * (pa[0].w + pa[2].w);
            m[4] = 0.5f * (pa[1].x + pa[3].x); m[5] = 0.5f * (pa[1].y + pa[3].y);
            m[6] = 0.5f * (pa[1].z + pa[3].z); m[7] = 0.5f * (pa[1].w + pa[3].w);
            short8 h8, l8;
            #pragma unroll
            for (int e = 0; e < 8; ++e) {
                unsigned short hh, ll;
                split_bf16(m[e], hh, ll);
                h8[e] = (short)hh; l8[e] = (short)ll;
            }
            *(short8*)&sAh[srow * 32 + sA] = h8;
            *(short8*)&sAl[srow * 32 + sA] = l8;
        }
        __syncthreads();   // drains A writes (lgkm) + B DMA (vmcnt)

        if (c < 15) {      // prefetch A chunk c+1 — drained at the NEXT barrier,
            const int k0 = (c + 1) * 32;   // hidden under this chunk's MFMAs
            pa[0] = *(const float4*)(a0p + k0);     pa[1] = *(const float4*)(a0p + k0 + 4);
            pa[2] = *(const float4*)(a1p + k0);     pa[3] = *(const float4*)(a1p + k0 + 4);
        }

        // ---- 3 MFMA passes; frag layout [m|n = lane&15][k = quad*8 + j]
        short8 aF[4], bF[4];
        #pragma unroll
        for (int mi = 0; mi < 4; ++mi) aF[mi] = *(const short8*)&sAh[(wr + mi * 16 + cid) * 32 + quad * 8];
        #pragma unroll
        for (int ni = 0; ni < 4; ++ni) bF[ni] = *(const short8*)&sBh[(wc + ni * 16 + cid) * 32 + quad * 8];
        #pragma unroll
        for (int mi = 0; mi < 4; ++mi)
            #pragma unroll
            for (int ni = 0; ni < 4; ++ni)
                acc[mi][ni] = __builtin_amdgcn_mfma_f32_16x16x32_bf16(aF[mi], bF[ni], acc[mi][ni], 0, 0, 0);
        #pragma unroll
        for (int mi = 0; mi < 4; ++mi) aF[mi] = *(const short8*)&sAl[(wr + mi * 16 + cid) * 32 + quad * 8];
        #pragma unroll
        for (int mi = 0; mi < 4; ++mi)
            #pragma unroll
            for (int ni = 0; ni < 4; ++ni)
                acc[mi][ni] = __builtin_amdgcn_mfma_f32_16x16x32_bf16(aF[mi], bF[ni], acc[mi][ni], 0, 0, 0);
        #pragma unroll
        for (int mi = 0; mi < 4; ++mi) aF[mi] = *(const short8*)&sAh[(wr + mi * 16 + cid) * 32 + quad * 8];
        #pragma unroll
        for (int ni = 0; ni < 4; ++ni) bF[ni] = *(const short8*)&sBl[(wc + ni * 16 + cid) * 32 + quad * 8];
        #pragma unroll
        for (int mi = 0; mi < 4; ++mi)
            #pragma unroll
            for (int ni = 0; ni < 4; ++ni)
                acc[mi][ni] = __builtin_amdgcn_mfma_f32_16x16x32_bf16(aF[mi], bF[ni], acc[mi][ni], 0, 0, 0);
        __syncthreads();   // drains frag reads (lgkm) + A prefetch (vmcnt)
    }

    // ---- epilogue: score + top-2; C/D layout col=lane&15, row=quad*4+reg
    float cq[4];
    #pragma unroll
    for (int ni = 0; ni < 4; ++ni) cq[ni] = cb_sq[colBase + wc + ni * 16 + cid];

    float4* sRed = (float4*)sMem;    // [row 128][cw 4][slot 4] = 32 KB
    #pragma unroll
    for (int mi = 0; mi < 4; ++mi) {
        #pragma unroll
        for (int reg = 0; reg < 4; ++reg) {
            float v1 = 3.4e38f, v2 = 3.4e38f;
            int   i1 = 0x7FFFFFFF, i2 = 0x7FFFFFFF;
            #pragma unroll
            for (int ni = 0; ni < 4; ++ni) {
                const float s = fmaf(-2.0f, acc[mi][ni][reg], cq[ni]);
                merge_cand(s, colBase + wc + ni * 16 + cid, v1, i1, v2, i2);
            }
            #pragma unroll
            for (int d = 1; d <= 2; d <<= 1) {
                float ov1 = __shfl_xor(v1, d); int oi1 = __shfl_xor(i1, d);
                float ov2 = __shfl_xor(v2, d); int oi2 = __shfl_xor(i2, d);
                merge_cand(ov1, oi1, v1, i1, v2, i2);
                merge_cand(ov2, oi2, v1, i1, v2, i2);
            }
            if ((cid & 3) == 0) {
                const int row = wr + mi * 16 + quad * 4 + reg;
                sRed[(row * 4 + cw) * 4 + (cid >> 2)] =
                    make_float4(v1, __int_as_float(i1), v2, __int_as_float(i2));
            }
        }
    }
    __syncthreads();
    if (tid < 128) {
        float v1 = 3.4e38f, v2 = 3.4e38f;
        int   i1 = 0x7FFFFFFF, i2 = 0x7FFFFFFF;
        #pragma unroll
        for (int e = 0; e < 16; ++e) {
            const float4 t = sRed[tid * 16 + e];
            merge_cand(t.x, __float_as_int(t.y), v1, i1, v2, i2);
            merge_cand(t.z, __float_as_int(t.w), v1, i1, v2, i2);
        }
        wsRed[(size_t)(rowBase + tid) * 8 + colb] =
            make_float4(v1, __int_as_float(i1), v2, __int_as_float(i2));
    }
}

// ---------------------------------------------------------------------------
// Kernel 4: merge 8 colblock results per row; write idx, flag ties, loss.
// ---------------------------------------------------------------------------
__global__ __launch_bounds__(256, 1)
void cra_merge(const float4* __restrict__ wsRed,
               const float* __restrict__ Sk,
               float* __restrict__ out_idx,
               float* __restrict__ out_loss,
               int* __restrict__ counter,
               int* __restrict__ flagRow,
               int2* __restrict__ flagI)
{
    __shared__ float sl[256];
    const int tid = threadIdx.x;
    const int r = blockIdx.x * 256 + tid;
    float v1 = 3.4e38f, v2 = 3.4e38f;
    int   i1 = 0x7FFFFFFF, i2 = 0x7FFFFFFF;
    #pragma unroll
    for (int cbk = 0; cbk < 8; ++cbk) {
        const float4 t = wsRed[(size_t)r * 8 + cbk];
        merge_cand(t.x, __float_as_int(t.y), v1, i1, v2, i2);
        merge_cand(t.z, __float_as_int(t.w), v1, i1, v2, i2);
    }
    out_idx[r] = (float)i1;
    if (v2 - v1 < EPS_GAP) {
        const int slot = atomicAdd(counter, 1);
        flagRow[slot] = r;
        flagI[slot] = make_int2(i1, i2);
    }
    sl[tid] = Sk[i1];
    __syncthreads();
    for (int s = 128; s > 0; s >>= 1) { if (tid < s) sl[tid] += sl[tid + s]; __syncthreads(); }
    if (tid == 0) atomicAdd(out_loss, sl[0] * LOSS_SCALE);
}

// ---------------------------------------------------------------------------
// Kernel 5: gather embeddings (overwrites the wsRed scratch region).
// ---------------------------------------------------------------------------
__global__ __launch_bounds__(256, 1)
void cra_gather(const float* __restrict__ out_idx,
                const float4* __restrict__ cb4,
                float4* __restrict__ out4)
{
    __shared__ int sidx[128];
    const int tid = threadIdx.x;
    const int rb = blockIdx.x * 128;
    if (tid < 128) sidx[tid] = (int)out_idx[rb + tid];
    __syncthreads();
    for (int j = tid; j < 128 * 128; j += 256) {
        const int row = j >> 7, q = j & 127;
        out4[(size_t)(rb + row) * 128 + q] = cb4[(size_t)sidx[row] * 128 + q];
    }
}

// ---------------------------------------------------------------------------
// Kernel 6: exact-f32 recheck of flagged rows' top-2 candidates.
// ---------------------------------------------------------------------------
__global__ __launch_bounds__(256, 1)
void cra_recheck(const float* __restrict__ ce,
                 const float* __restrict__ cb,
                 const float* __restrict__ cb_sq,
                 const float* __restrict__ Sk,
                 const int* __restrict__ counter,
                 const int* __restrict__ flagRow,
                 const int2* __restrict__ flagI,
                 float* __restrict__ out_idx,
                 float4* __restrict__ out4,
                 float* __restrict__ out_loss,
                 const float4* __restrict__ cb4)
{
    __shared__ float rp[8];
    __shared__ int swin;
    const int tid = threadIdx.x;
    const int n = counter[0];
    for (int f = blockIdx.x; f < n; f += 64) {
        const int row = flagRow[f];
        const int2 ii = flagI[f];
        const int d0 = tid * 2;
        const float2 x0 = *(const float2*)(ce + (size_t)(2 * row) * D_DIM + d0);
        const float2 x1 = *(const float2*)(ce + (size_t)(2 * row) * D_DIM + D_DIM + d0);
        const float m0 = 0.5f * (x0.x + x1.x), m1 = 0.5f * (x0.y + x1.y);
        const float* c1 = cb + (size_t)ii.x * D_DIM + d0;
        const float* c2 = cb + (size_t)ii.y * D_DIM + d0;
        float p1 = fmaf(m0, c1[0], m1 * c1[1]);
        float p2 = fmaf(m0, c2[0], m1 * c2[1]);
        #pragma unroll
        for (int off = 32; off > 0; off >>= 1) {
            p1 += __shfl_down(p1, off, 64);
            p2 += __shfl_down(p2, off, 64);
        }
        if ((tid & 63) == 0) { rp[(tid >> 6) * 2] = p1; rp[(tid >> 6) * 2 + 1] = p2; }
        __syncthreads();
        if (tid == 0) {
            const float dot1 = rp[0] + rp[2] + rp[4] + rp[6];
            const float dot2 = rp[1] + rp[3] + rp[5] + rp[7];
            const float s1 = cb_sq[ii.x] - 2.f * dot1;
            const float s2 = cb_sq[ii.y] - 2.f * dot2;
            const int win = (s2 < s1 || (s2 == s1 && ii.y < ii.x)) ? ii.y : ii.x;
            swin = win;
            if (win != ii.x) {
                out_idx[row] = (float)win;
                atomicAdd(out_loss, (Sk[win] - Sk[ii.x]) * LOSS_SCALE);
            }
        }
        __syncthreads();
        if (swin != ii.x) {
            for (int q = tid; q < 128; q += 256)
                out4[(size_t)row * 128 + q] = cb4[(size_t)swin * 128 + q];
        }
        __syncthreads();
    }
}

// ---------------------------------------------------------------------------
extern "C" void kernel_launch(void* const* d_in, const int* in_sizes, int n_in,
                              void* d_out, int out_size, void* d_ws, size_t ws_size,
                              hipStream_t stream)
{
    // inputs: 0 char_tokens (unused), 1 char_embeddings, 2 word_codebook,
    //         3 proj_w, 4 proj_b
    const float* ce = (const float*)d_in[1];
    const float* cb = (const float*)d_in[2];
    const float* W  = (const float*)d_in[3];
    const float* pb = (const float*)d_in[4];

    char* ws = (char*)d_ws;                                  // ~4.5 MB used
    unsigned short* wsBh = (unsigned short*)ws;              // 2 MB images
    unsigned short* wsBl = (unsigned short*)(ws + 2097152);  // 2 MB
    float* cb_sq   = (float*)(ws + 4194304);
    float* Sk      = (float*)(ws + 4194304 + 8192);
    int*   flagRow = (int*)(ws + 4194304 + 16384);
    int2*  flagI   = (int2*)(ws + 4194304 + 16384 + 131072);
    int*   counter = (int*)(ws + 4194304 + 16384 + 131072 + 262144);

    float* out_idx  = (float*)d_out;
    float* out_emb  = out_idx + N_ROWS;
    float* out_loss = out_emb + (size_t)N_ROWS * D_DIM;
    float4* wsRed   = (float4*)out_emb;   // 4 MB scratch inside emb region (pre-gather)

    hipMemsetAsync(Sk, 0, K_CODES * sizeof(float), stream);
    hipMemsetAsync(counter, 0, sizeof(int), stream);
    hipMemsetAsync(out_loss, 0, sizeof(float), stream);

    cra_pack<<<64, 256, 0, stream>>>(cb, wsBh, wsBl, cb_sq);
    cra_proj<<<256, 256, 0, stream>>>(cb, W, pb, Sk);
    cra_gemm<<<2048, 512, 0, stream>>>(ce, wsBh, wsBl, cb_sq, wsRed);
    cra_merge<<<128, 256, 0, stream>>>(wsRed, Sk, out_idx, out_loss, counter, flagRow, flagI);
    cra_gather<<<256, 256, 0, stream>>>(out_idx, (const float4*)cb, (float4*)out_emb);
    cra_recheck<<<64, 256, 0, stream>>>(ce, cb, cb_sq, Sk, counter, flagRow, flagI,
                                        out_idx, (float4*)out_emb, out_loss, (const float4*)cb);
}

// Round 5
// 867.357 us; speedup vs baseline: 1.5120x; 1.0962x over previous
//
#include <hip/hip_runtime.h>

// SimpleCRA round 5: virtual-K split-bf16 GEMM in the m97 template.
// dot = ah*bh + al*bh + ah*bl folded into ONE plain bf16 GEMM with K'=1536:
//   A' = [Ah chunks 0-15 | Al chunks 16-31]   (64 MiB, packed into emb region)
//   B' = [Bh chunks 0-15 | Bl chunks 16-31]   (4 MB ws)
//   chunk g: ach = g&31, bch = (g&15)|((g&32)>>1)
// Hot loop per wave per chunk: 4 global_load_lds(16B) + 8 ds_read_b128 +
// 16 mfma_f32_16x16x32_bf16 — m97's measured-874TF instruction mix.
// Residual (al*bl) ~5e-7 << EPS 1e-5; tie rows exactly rechecked (R3/R4-proven).

#define D_DIM    512
#define K_CODES  2048
#define N_ROWS   32768
#define EPS_GAP  1e-5f
#define LOSS_SCALE (1.0f / 16777216.0f)   // 1/(N_ROWS*D_DIM)

typedef __attribute__((ext_vector_type(8))) short short8;   // 8 bf16 (4 VGPR)
typedef __attribute__((ext_vector_type(4))) float f32x4;    // MFMA C/D

__device__ __forceinline__ void split_bf16(float f, unsigned short& h, unsigned short& l) {
    unsigned u = __float_as_uint(f);
    h = (unsigned short)(u >> 16);                       // truncation split
    float hr = __uint_as_float(u & 0xFFFF0000u);
    l = (unsigned short)(__float_as_uint(f - hr) >> 16);
}

// async global->LDS DMA, 16 B/lane; lds ptr wave-uniform, HW adds lane*16.
__device__ __forceinline__ void dma16(const void* g, void* l) {
    __builtin_amdgcn_global_load_lds(
        (const __attribute__((address_space(1))) unsigned int*)g,
        (__attribute__((address_space(3))) unsigned int*)l, 16, 0, 0);
}

// insert candidate into sorted-2 list ordered by (val, idx) — total order,
// merge-order independent; matches numpy first-occurrence argmin.
__device__ __forceinline__ void merge_cand(float s, int idx, float& v1, int& i1, float& v2, int& i2) {
    if (s < v1 || (s == v1 && idx < i1)) { v2 = v1; i2 = i1; v1 = s; i1 = idx; }
    else if (s < v2 || (s == v2 && idx < i2)) { v2 = s; i2 = idx; }
}

// ---------------------------------------------------------------------------
// Kernel 1: pack A' images. Block = one mb (128 mean-rows); layout
// [mb 256][ach 32][row 128][k 32] shorts, ach 0-15 = Ah, 16-31 = Al.
// ---------------------------------------------------------------------------
__global__ __launch_bounds__(256, 1)
void cra_pack_a(const float* __restrict__ ce,
                unsigned short* __restrict__ Ap)
{
    const int tid = threadIdx.x;
    const int mb  = blockIdx.x;
    const int rq  = tid >> 5;            // row slice 0..7
    const int dq  = tid & 31;            // 16-float span index
    const int dbase = dq * 16;
    const int ach = dq >> 1;             // 0..15
    const int k0  = (dq & 1) * 16;

    #pragma unroll 2
    for (int p = 0; p < 16; ++p) {
        const int r  = p * 8 + rq;       // 0..127
        const int gr = mb * 128 + r;
        const float* a0 = ce + (size_t)(2 * gr) * D_DIM + dbase;
        const float* a1 = a0 + D_DIM;
        float4 x0[4], x1[4];
        #pragma unroll
        for (int q = 0; q < 4; ++q) {
            x0[q] = *(const float4*)(a0 + q * 4);
            x1[q] = *(const float4*)(a1 + q * 4);
        }
        short8 h8[2], l8[2];
        #pragma unroll
        for (int q = 0; q < 4; ++q) {
            const float m[4] = {0.5f * (x0[q].x + x1[q].x), 0.5f * (x0[q].y + x1[q].y),
                                0.5f * (x0[q].z + x1[q].z), 0.5f * (x0[q].w + x1[q].w)};
            #pragma unroll
            for (int e = 0; e < 4; ++e) {
                unsigned short hh, ll;
                split_bf16(m[e], hh, ll);
                h8[q >> 1][(q & 1) * 4 + e] = (short)hh;
                l8[q >> 1][(q & 1) * 4 + e] = (short)ll;
            }
        }
        const size_t hb = ((size_t)(mb * 32 + ach) * 128 + r) * 32 + k0;
        const size_t lb = ((size_t)(mb * 32 + 16 + ach) * 128 + r) * 32 + k0;
        *(short8*)(Ap + hb)     = h8[0];
        *(short8*)(Ap + hb + 8) = h8[1];
        *(short8*)(Ap + lb)     = l8[0];
        *(short8*)(Ap + lb + 8) = l8[1];
    }
}

// ---------------------------------------------------------------------------
// Kernel 2: pack B' images [colb 16][bch 32][row 128][k 32] + cb_sq; block 0
// zeros Sk / counter / loss. 64 blocks x 256 thr, 32 codes per block.
// ---------------------------------------------------------------------------
__global__ __launch_bounds__(256, 1)
void cra_pack_b(const float* __restrict__ cb,
                unsigned short* __restrict__ Bp,
                float* __restrict__ cb_sq,
                float* __restrict__ Sk,
                int* __restrict__ counter,
                float* __restrict__ loss_out)
{
    __shared__ float cbs[32 * D_DIM];    // 64 KB
    const int tid = threadIdx.x;
    const int c0  = blockIdx.x * 32;

    if (blockIdx.x == 0) {
        #pragma unroll
        for (int j = 0; j < 8; ++j) Sk[tid + j * 256] = 0.0f;
        if (tid == 0) { counter[0] = 0; loss_out[0] = 0.0f; }
    }

    {   // stage 32 codebook rows, coalesced float4
        const float4* src = (const float4*)(cb + (size_t)c0 * D_DIM);
        float4* dst = (float4*)cbs;
        #pragma unroll
        for (int k = 0; k < 16; ++k) dst[tid + k * 256] = src[tid + k * 256];
    }
    __syncthreads();

    if (tid < 32) {
        const float* r = cbs + tid * D_DIM;
        float s = 0.f;
        for (int d = 0; d < D_DIM; ++d) s = fmaf(r[d], r[d], s);
        cb_sq[c0 + tid] = s;
    }

    // pack: thread owns local row (tid>>3), elems dspan..dspan+63
    const int row  = tid >> 3;
    const int k    = c0 + row;
    const int colb = k >> 7;             // 0..15
    const int pr   = k & 127;
    const int dspan = (tid & 7) * 64;
    #pragma unroll
    for (int g = 0; g < 8; ++g) {
        const int d   = dspan + g * 8;
        const int bch = d >> 5;
        const int k0  = d & 31;
        short8 h8, l8;
        #pragma unroll
        for (int e = 0; e < 8; ++e) {
            unsigned short hh, ll;
            split_bf16(cbs[row * D_DIM + d + e], hh, ll);
            h8[e] = (short)hh; l8[e] = (short)ll;
        }
        *(short8*)(Bp + ((size_t)(colb * 32 + bch) * 128 + pr) * 32 + k0)      = h8;
        *(short8*)(Bp + ((size_t)(colb * 32 + 16 + bch) * 128 + pr) * 32 + k0) = l8;
    }
}

// ---------------------------------------------------------------------------
// Kernel 3: Sk[k] = ||cb[k]@W^T + pb - cb[k]||^2, atomically accumulated
// (Sk zeroed by pack_b). 256 blocks = 64 code-blocks x 4 e-blocks.
// ---------------------------------------------------------------------------
__global__ __launch_bounds__(256, 1)
void cra_proj(const float* __restrict__ cb,
              const float* __restrict__ W,
              const float* __restrict__ pb,
              float* __restrict__ Sk)
{
    __shared__ float cbs[32 * D_DIM];    // 64 KB
    __shared__ float red[4 * 32];
    const int tid = threadIdx.x;
    const int cblock = blockIdx.x >> 2;
    const int eb     = blockIdx.x & 3;
    const int c0 = cblock * 32;

    {
        const float4* src = (const float4*)(cb + (size_t)c0 * D_DIM);
        float4* dst = (float4*)cbs;
        #pragma unroll
        for (int k = 0; k < 16; ++k) dst[tid + k * 256] = src[tid + k * 256];
    }
    __syncthreads();

    const int e  = eb * 128 + (tid >> 1);
    const int dh = (tid & 1) * 256;
    float acc[32];
    #pragma unroll
    for (int c = 0; c < 32; ++c) acc[c] = 0.f;
    const float4* wrow = (const float4*)(W + (size_t)e * D_DIM + dh);
    for (int dq = 0; dq < 64; ++dq) {
        const float4 wv = wrow[dq];
        #pragma unroll
        for (int c = 0; c < 32; ++c) {
            const float4 cv = *(const float4*)&cbs[c * D_DIM + dh + dq * 4];
            acc[c] += cv.x * wv.x + cv.y * wv.y + cv.z * wv.z + cv.w * wv.w;
        }
    }
    const float bias = pb[e];
    const int w = tid >> 6;
    #pragma unroll
    for (int c = 0; c < 32; ++c) {
        const float full = acc[c] + __shfl_xor(acc[c], 1);
        const float diff = full + bias - cbs[c * D_DIM + e];
        float v = (tid & 1) ? 0.f : diff * diff;
        #pragma unroll
        for (int off = 32; off > 0; off >>= 1) v += __shfl_down(v, off, 64);
        if ((tid & 63) == 0) red[w * 32 + c] = v;
    }
    __syncthreads();
    if (tid < 32)
        atomicAdd(&Sk[c0 + tid],
                  red[tid] + red[32 + tid] + red[64 + tid] + red[96 + tid]);
}

// ---------------------------------------------------------------------------
// Kernel 4: the m97-template GEMM. 4096 blocks (256 mb x 16 colb, XCD-swizzled),
// 256 thr / 4 waves, tile 128x128, wave 64x64 = 4x4 of 16x16x32, K' = 1536
// (48 chunks of 32). LDS 16 KB single-buffered.
// ---------------------------------------------------------------------------
__global__ __launch_bounds__(256, 3)
void cra_gemm(const unsigned short* __restrict__ Ap,
              const unsigned short* __restrict__ Bp,
              const float* __restrict__ cb_sq,
              float4* __restrict__ wsRed)           // [32768][16] {v1,i1,v2,i2}
{
    __shared__ short sMem[8192];         // 16 KB: sA 128x32, sB 128x32
    short* sA = sMem;
    short* sB = sMem + 4096;

    const int tid  = threadIdx.x;
    const int bid  = blockIdx.x;
    const int xcd  = bid & 7;
    const int slot = bid >> 3;           // 0..511
    const int mb   = xcd * 32 + (slot >> 4);
    const int colb = slot & 15;
    const int rowBase = mb * 128;
    const int colBase = colb * 128;

    const int lane = tid & 63;
    const int w    = tid >> 6;           // 0..3
    const int wr   = (w & 1) * 64;
    const int wcH  = w >> 1;             // 0..1
    const int wc   = wcH * 64;
    const int cid  = lane & 15;
    const int quad = lane >> 4;

    f32x4 acc[4][4];
    #pragma unroll
    for (int i = 0; i < 4; ++i)
        #pragma unroll
        for (int j = 0; j < 4; ++j) acc[i][j] = (f32x4)(0.f);

    // DMA geometry: chunk image = 8 KB contiguous; wave w covers 2 KB via
    // two 16B/lane instructions.
    const char* Ag = (const char*)Ap + ((size_t)mb   * 32) * 8192 + w * 2048 + lane * 16;
    const char* Bg = (const char*)Bp + ((size_t)colb * 32) * 8192 + w * 2048 + lane * 16;
    char* lA = (char*)sA + w * 2048;
    char* lB = (char*)sB + w * 2048;

    #pragma unroll 1
    for (int g = 0; g < 48; ++g) {
        const int ach = g & 31;
        const int bch = (g & 15) | ((g & 32) >> 1);
        const char* ag = Ag + ach * 8192;
        const char* bg = Bg + bch * 8192;
        dma16(ag,        lA);
        dma16(ag + 1024, lA + 1024);
        dma16(bg,        lB);
        dma16(bg + 1024, lB + 1024);
        __syncthreads();                 // drain DMA (vmcnt) before reads

        short8 aF[4], bF[4];
        #pragma unroll
        for (int mi = 0; mi < 4; ++mi) aF[mi] = *(const short8*)&sA[(wr + mi * 16 + cid) * 32 + quad * 8];
        #pragma unroll
        for (int ni = 0; ni < 4; ++ni) bF[ni] = *(const short8*)&sB[(wc + ni * 16 + cid) * 32 + quad * 8];
        #pragma unroll
        for (int mi = 0; mi < 4; ++mi)
            #pragma unroll
            for (int ni = 0; ni < 4; ++ni)
                acc[mi][ni] = __builtin_amdgcn_mfma_f32_16x16x32_bf16(aF[mi], bF[ni], acc[mi][ni], 0, 0, 0);
        __syncthreads();                 // frag reads done before next DMA writes
    }

    // ---- epilogue: score + top-2; C/D layout col=lane&15, row=quad*4+reg
    float cq[4];
    #pragma unroll
    for (int ni = 0; ni < 4; ++ni) cq[ni] = cb_sq[colBase + wc + ni * 16 + cid];

    float4* sRed = (float4*)sMem;        // [row 128][wcH 2][slot 4] = 16 KB
    #pragma unroll
    for (int mi = 0; mi < 4; ++mi) {
        #pragma unroll
        for (int reg = 0; reg < 4; ++reg) {
            float v1 = 3.4e38f, v2 = 3.4e38f;
            int   i1 = 0x7FFFFFFF, i2 = 0x7FFFFFFF;
            #pragma unroll
            for (int ni = 0; ni < 4; ++ni) {
                const float s = fmaf(-2.0f, acc[mi][ni][reg], cq[ni]);
                merge_cand(s, colBase + wc + ni * 16 + cid, v1, i1, v2, i2);
            }
            #pragma unroll
            for (int d = 1; d <= 2; d <<= 1) {
                float ov1 = __shfl_xor(v1, d); int oi1 = __shfl_xor(i1, d);
                float ov2 = __shfl_xor(v2, d); int oi2 = __shfl_xor(i2, d);
                merge_cand(ov1, oi1, v1, i1, v2, i2);
                merge_cand(ov2, oi2, v1, i1, v2, i2);
            }
            if ((cid & 3) == 0) {
                const int row = wr + mi * 16 + quad * 4 + reg;
                sRed[(row * 2 + wcH) * 4 + (cid >> 2)] =
                    make_float4(v1, __int_as_float(i1), v2, __int_as_float(i2));
            }
        }
    }
    __syncthreads();
    if (tid < 128) {
        float v1 = 3.4e38f, v2 = 3.4e38f;
        int   i1 = 0x7FFFFFFF, i2 = 0x7FFFFFFF;
        #pragma unroll
        for (int e = 0; e < 8; ++e) {
            const float4 t = sRed[tid * 8 + e];
            merge_cand(t.x, __float_as_int(t.y), v1, i1, v2, i2);
            merge_cand(t.z, __float_as_int(t.w), v1, i1, v2, i2);
        }
        wsRed[(size_t)(rowBase + tid) * 16 + colb] =
            make_float4(v1, __int_as_float(i1), v2, __int_as_float(i2));
    }
}

// ---------------------------------------------------------------------------
// Kernel 5: merge 16 colblock results per row; write idx, flag ties, loss.
// ---------------------------------------------------------------------------
__global__ __launch_bounds__(256, 1)
void cra_merge(const float4* __restrict__ wsRed,
               const float* __restrict__ Sk,
               float* __restrict__ out_idx,
               float* __restrict__ out_loss,
               int* __restrict__ counter,
               int* __restrict__ flagRow,
               int2* __restrict__ flagI)
{
    __shared__ float sl[256];
    const int tid = threadIdx.x;
    const int r = blockIdx.x * 256 + tid;
    float v1 = 3.4e38f, v2 = 3.4e38f;
    int   i1 = 0x7FFFFFFF, i2 = 0x7FFFFFFF;
    #pragma unroll 4
    for (int cbk = 0; cbk < 16; ++cbk) {
        const float4 t = wsRed[(size_t)r * 16 + cbk];
        merge_cand(t.x, __float_as_int(t.y), v1, i1, v2, i2);
        merge_cand(t.z, __float_as_int(t.w), v1, i1, v2, i2);
    }
    out_idx[r] = (float)i1;
    if (v2 - v1 < EPS_GAP) {
        const int slot = atomicAdd(counter, 1);
        flagRow[slot] = r;
        flagI[slot] = make_int2(i1, i2);
    }
    sl[tid] = Sk[i1];
    __syncthreads();
    for (int s = 128; s > 0; s >>= 1) { if (tid < s) sl[tid] += sl[tid + s]; __syncthreads(); }
    if (tid == 0) atomicAdd(out_loss, sl[0] * LOSS_SCALE);
}

// ---------------------------------------------------------------------------
// Kernel 6: gather embeddings (overwrites the A' image region).
// ---------------------------------------------------------------------------
__global__ __launch_bounds__(256, 1)
void cra_gather(const float* __restrict__ out_idx,
                const float4* __restrict__ cb4,
                float4* __restrict__ out4)
{
    __shared__ int sidx[128];
    const int tid = threadIdx.x;
    const int rb = blockIdx.x * 128;
    if (tid < 128) sidx[tid] = (int)out_idx[rb + tid];
    __syncthreads();
    for (int j = tid; j < 128 * 128; j += 256) {
        const int row = j >> 7, q = j & 127;
        out4[(size_t)(rb + row) * 128 + q] = cb4[(size_t)sidx[row] * 128 + q];
    }
}

// ---------------------------------------------------------------------------
// Kernel 7: exact-f32 recheck of flagged rows' top-2 candidates.
// ---------------------------------------------------------------------------
__global__ __launch_bounds__(256, 1)
void cra_recheck(const float* __restrict__ ce,
                 const float* __restrict__ cb,
                 const float* __restrict__ cb_sq,
                 const float* __restrict__ Sk,
                 const int* __restrict__ counter,
                 const int* __restrict__ flagRow,
                 const int2* __restrict__ flagI,
                 float* __restrict__ out_idx,
                 float4* __restrict__ out4,
                 float* __restrict__ out_loss,
                 const float4* __restrict__ cb4)
{
    __shared__ float rp[8];
    __shared__ int swin;
    const int tid = threadIdx.x;
    const int n = counter[0];
    for (int f = blockIdx.x; f < n; f += 64) {
        const int row = flagRow[f];
        const int2 ii = flagI[f];
        const int d0 = tid * 2;
        const float2 x0 = *(const float2*)(ce + (size_t)(2 * row) * D_DIM + d0);
        const float2 x1 = *(const float2*)(ce + (size_t)(2 * row) * D_DIM + D_DIM + d0);
        const float m0 = 0.5f * (x0.x + x1.x), m1 = 0.5f * (x0.y + x1.y);
        const float* c1 = cb + (size_t)ii.x * D_DIM + d0;
        const float* c2 = cb + (size_t)ii.y * D_DIM + d0;
        float p1 = fmaf(m0, c1[0], m1 * c1[1]);
        float p2 = fmaf(m0, c2[0], m1 * c2[1]);
        #pragma unroll
        for (int off = 32; off > 0; off >>= 1) {
            p1 += __shfl_down(p1, off, 64);
            p2 += __shfl_down(p2, off, 64);
        }
        if ((tid & 63) == 0) { rp[(tid >> 6) * 2] = p1; rp[(tid >> 6) * 2 + 1] = p2; }
        __syncthreads();
        if (tid == 0) {
            const float dot1 = rp[0] + rp[2] + rp[4] + rp[6];
            const float dot2 = rp[1] + rp[3] + rp[5] + rp[7];
            const float s1 = cb_sq[ii.x] - 2.f * dot1;
            const float s2 = cb_sq[ii.y] - 2.f * dot2;
            const int win = (s2 < s1 || (s2 == s1 && ii.y < ii.x)) ? ii.y : ii.x;
            swin = win;
            if (win != ii.x) {
                out_idx[row] = (float)win;
                atomicAdd(out_loss, (Sk[win] - Sk[ii.x]) * LOSS_SCALE);
            }
        }
        __syncthreads();
        if (swin != ii.x) {
            for (int q = tid; q < 128; q += 256)
                out4[(size_t)row * 128 + q] = cb4[(size_t)swin * 128 + q];
        }
        __syncthreads();
    }
}

// ---------------------------------------------------------------------------
extern "C" void kernel_launch(void* const* d_in, const int* in_sizes, int n_in,
                              void* d_out, int out_size, void* d_ws, size_t ws_size,
                              hipStream_t stream)
{
    // inputs: 0 char_tokens (unused), 1 char_embeddings, 2 word_codebook,
    //         3 proj_w, 4 proj_b
    const float* ce = (const float*)d_in[1];
    const float* cb = (const float*)d_in[2];
    const float* W  = (const float*)d_in[3];
    const float* pb = (const float*)d_in[4];

    char* ws = (char*)d_ws;                                  // ~13 MB used
    unsigned short* Bp = (unsigned short*)ws;                // 4 MB B' images
    float4* wsRed  = (float4*)(ws + 4194304);                // 8 MB top-2 scratch
    float* cb_sq   = (float*)(ws + 12582912);
    float* Sk      = (float*)(ws + 12582912 + 8192);
    int*   flagRow = (int*)(ws + 12582912 + 16384);
    int2*  flagI   = (int2*)(ws + 12582912 + 16384 + 131072);
    int*   counter = (int*)(ws + 12582912 + 16384 + 131072 + 262144);

    float* out_idx  = (float*)d_out;
    float* out_emb  = out_idx + N_ROWS;
    float* out_loss = out_emb + (size_t)N_ROWS * D_DIM;
    // A' images (64 MiB) live in the emb output region until gather overwrites.
    unsigned short* Ap = (unsigned short*)out_emb;

    cra_pack_a<<<256, 256, 0, stream>>>(ce, Ap);
    cra_pack_b<<<64, 256, 0, stream>>>(cb, Bp, cb_sq, Sk, counter, out_loss);
    cra_proj<<<256, 256, 0, stream>>>(cb, W, pb, Sk);
    cra_gemm<<<4096, 256, 0, stream>>>(Ap, Bp, cb_sq, wsRed);
    cra_merge<<<128, 256, 0, stream>>>(wsRed, Sk, out_idx, out_loss, counter, flagRow, flagI);
    cra_gather<<<256, 256, 0, stream>>>(out_idx, (const float4*)cb, (float4*)out_emb);
    cra_recheck<<<64, 256, 0, stream>>>(ce, cb, cb_sq, Sk, counter, flagRow, flagI,
                                        out_idx, (float4*)out_emb, out_loss, (const float4*)cb);
}